// Round 8
// baseline (559.323 us; speedup 1.0000x reference)
//
#include <hip/hip_runtime.h>
#include <math.h>

typedef __attribute__((ext_vector_type(4))) float f32x4;
typedef __attribute__((ext_vector_type(4))) float f4;
typedef __attribute__((ext_vector_type(8))) _Float16 h8;
typedef __attribute__((ext_vector_type(8))) unsigned short us8;

static __device__ __forceinline__ h8 ld8h(const _Float16* p) {
    return __builtin_bit_cast(h8, *(const us8*)p);
}
static __device__ __forceinline__ void glds16(const void* g, void* l) {
    __builtin_amdgcn_global_load_lds((const __attribute__((address_space(1))) unsigned int*)g,
                                     (__attribute__((address_space(3))) unsigned int*)l, 16, 0, 0);
}

// ---------------------------------------------------------------------------
// fp32 -> fp16, 8 elements/thread
// ---------------------------------------------------------------------------
__global__ void convert_half(const float* __restrict__ in, _Float16* __restrict__ out, int n8) {
    int i = blockIdx.x * blockDim.x + threadIdx.x;
    if (i >= n8) return;
    f4 v0 = *(const f4*)(in + (size_t)i * 8);
    f4 v1 = *(const f4*)(in + (size_t)i * 8 + 4);
    h8 o;
#pragma unroll
    for (int j = 0; j < 4; j++) {
        o[j] = (_Float16)v0[j];
        o[j + 4] = (_Float16)v1[j];
    }
    *(h8*)(out + (size_t)i * 8) = o;
}

// ---------------------------------------------------------------------------
// 256x256 deep-pipeline GEMM (C = A @ B^T, fp16 in, fp32 out).
// 512 thr = 8 waves (2m x 4n), per-wave 128x64 (8x4 frags): 12 ds_read per
// 32 MFMA/wave. BK=32, ring-3 LDS (96 KB, 1 block/CU), stages 2 K-tiles
// ahead, ONE vmcnt(4)+s_barrier per K-tile (never drains until last tile).
// XOR swizzle slot^=(row>>1)&3 on glds source + read side: 0 bank conflicts.
// Race-freedom: stage(t+2) targets buf[(t+2)%3]=buf[(t-1)%3]; issued only
// after barrier(t), by which time all waves consumed buf[(t-1)%3] (their
// ds_reads are lgkm-waited before their tile-(t-1) MFMAs).
// ---------------------------------------------------------------------------
__global__ __launch_bounds__(512, 2) void gemm256(
    const _Float16* __restrict__ A, const _Float16* __restrict__ B,
    float* __restrict__ C, int M, int N, int K) {
    __shared__ _Float16 As[3][256][32], Bs[3][256][32];
    const int t = threadIdx.x;
    const int lane = t & 63, w = t >> 6;
    const int bm = blockIdx.y * 256, bn = blockIdx.x * 256;
    const int wm = w >> 2, wn = w & 3;
    const int l15 = lane & 15, l4 = lane >> 4;

    // staging: 1024 16B chunks per matrix, 2 per thread each
    const int c0 = t, c1 = t + 512;
    const int r0 = c0 >> 2, s0 = (((c0 & 3) ^ ((r0 >> 1) & 3)) * 8);
    const int r1 = c1 >> 2, s1 = (((c1 & 3) ^ ((r1 >> 1) & 3)) * 8);
    const int scol = ((l4 ^ ((l15 >> 1) & 3)) * 8);

    f32x4 acc[8][4] = {};
    const int NT = K >> 5;

#define STG(kt, bf)                                                            \
    {                                                                          \
        const int k0_ = (kt) << 5;                                             \
        glds16(A + (size_t)(bm + r0) * K + k0_ + s0, &As[(bf)][0][0] + c0 * 8);\
        glds16(A + (size_t)(bm + r1) * K + k0_ + s1, &As[(bf)][0][0] + c1 * 8);\
        glds16(B + (size_t)(bn + r0) * K + k0_ + s0, &Bs[(bf)][0][0] + c0 * 8);\
        glds16(B + (size_t)(bn + r1) * K + k0_ + s1, &Bs[(bf)][0][0] + c1 * 8);\
    }

    STG(0, 0)
    STG(1, 1)

    int bc = 0;
    for (int tt = 0; tt < NT; ++tt) {
        if (tt < NT - 1) asm volatile("s_waitcnt vmcnt(4)" ::: "memory");
        else             asm volatile("s_waitcnt vmcnt(0)" ::: "memory");
        __builtin_amdgcn_s_barrier();
        if (tt + 2 < NT) {
            const int nb = (bc + 2 >= 3) ? bc - 1 : bc + 2;
            STG(tt + 2, nb)
        }

        // phase 0: B frags + A frags 0..3, 16 MFMA
        h8 bfr[4], afr[4];
#pragma unroll
        for (int n = 0; n < 4; n++) bfr[n] = ld8h(&Bs[bc][wn * 64 + n * 16 + l15][scol]);
#pragma unroll
        for (int m = 0; m < 4; m++) afr[m] = ld8h(&As[bc][wm * 128 + m * 16 + l15][scol]);
        __builtin_amdgcn_s_setprio(1);
#pragma unroll
        for (int m = 0; m < 4; m++)
#pragma unroll
            for (int n = 0; n < 4; n++)
                acc[m][n] = __builtin_amdgcn_mfma_f32_16x16x32_f16(afr[m], bfr[n], acc[m][n], 0, 0, 0);
        __builtin_amdgcn_s_setprio(0);

        // phase 1: A frags 4..7, 16 MFMA
#pragma unroll
        for (int m = 0; m < 4; m++) afr[m] = ld8h(&As[bc][wm * 128 + (m + 4) * 16 + l15][scol]);
        __builtin_amdgcn_s_setprio(1);
#pragma unroll
        for (int m = 0; m < 4; m++)
#pragma unroll
            for (int n = 0; n < 4; n++)
                acc[m + 4][n] = __builtin_amdgcn_mfma_f32_16x16x32_f16(afr[m], bfr[n], acc[m + 4][n], 0, 0, 0);
        __builtin_amdgcn_s_setprio(0);

        bc = (bc == 2) ? 0 : bc + 1;
    }
#undef STG

#pragma unroll
    for (int m = 0; m < 8; m++)
#pragma unroll
        for (int n = 0; n < 4; n++)
#pragma unroll
            for (int r = 0; r < 4; r++)
                C[(size_t)(bm + wm * 128 + m * 16 + l4 * 4 + r) * N + bn + wn * 64 + n * 16 + l15] =
                    acc[m][n][r];
}

// ---------------------------------------------------------------------------
// R6 GEMM for the (smaller) projection: 128x128, dbuf, 0-conflict swizzle.
// ---------------------------------------------------------------------------
__global__ __launch_bounds__(256, 3) void gemm_fp16(
    const _Float16* __restrict__ A, const _Float16* __restrict__ B,
    float* __restrict__ C, int M, int N, int K) {
    __shared__ _Float16 As[2][128][32], Bs[2][128][32];
    const int t = threadIdx.x;
    const int lane = t & 63, w = t >> 6;
    const int bm = blockIdx.y * 128, bn = blockIdx.x * 128;
    const int wy = w >> 1, wx = w & 1;
    const int l15 = lane & 15, l4 = lane >> 4;

    const int c0 = (w * 2 + 0) * 64 + lane;
    const int c1 = (w * 2 + 1) * 64 + lane;
    const int r0s = c0 >> 2, s0 = (((c0 & 3) ^ ((r0s >> 1) & 3)) * 8);
    const int r1s = c1 >> 2, s1 = (((c1 & 3) ^ ((r1s >> 1) & 3)) * 8);

    f32x4 acc[4][4] = {};

    glds16(A + (size_t)(bm + r0s) * K + s0, &As[0][0][0] + c0 * 8);
    glds16(A + (size_t)(bm + r1s) * K + s1, &As[0][0][0] + c1 * 8);
    glds16(B + (size_t)(bn + r0s) * K + s0, &Bs[0][0][0] + c0 * 8);
    glds16(B + (size_t)(bn + r1s) * K + s1, &Bs[0][0][0] + c1 * 8);

    int cry[4], crx[4];
#pragma unroll
    for (int m = 0; m < 4; m++) {
        const int rowA = wy * 64 + m * 16 + l15;
        cry[m] = ((l4 ^ ((rowA >> 1) & 3)) * 8);
        const int rowB = wx * 64 + m * 16 + l15;
        crx[m] = ((l4 ^ ((rowB >> 1) & 3)) * 8);
    }

    int cur = 0;
    for (int k0 = 0; k0 < K; k0 += 32) {
        __syncthreads();
        const int nk = k0 + 32;
        if (nk < K) {
            _Float16* an = &As[cur ^ 1][0][0];
            _Float16* bn_ = &Bs[cur ^ 1][0][0];
            glds16(A + (size_t)(bm + r0s) * K + nk + s0, an + c0 * 8);
            glds16(A + (size_t)(bm + r1s) * K + nk + s1, an + c1 * 8);
            glds16(B + (size_t)(bn + r0s) * K + nk + s0, bn_ + c0 * 8);
            glds16(B + (size_t)(bn + r1s) * K + nk + s1, bn_ + c1 * 8);
        }
        h8 af[4], bf[4];
#pragma unroll
        for (int m = 0; m < 4; m++) af[m] = ld8h(&As[cur][wy * 64 + m * 16 + l15][cry[m]]);
#pragma unroll
        for (int n = 0; n < 4; n++) bf[n] = ld8h(&Bs[cur][wx * 64 + n * 16 + l15][crx[n]]);
#pragma unroll
        for (int m = 0; m < 4; m++)
#pragma unroll
            for (int n = 0; n < 4; n++)
                acc[m][n] = __builtin_amdgcn_mfma_f32_16x16x32_f16(af[m], bf[n], acc[m][n], 0, 0, 0);
        cur ^= 1;
    }

#pragma unroll
    for (int m = 0; m < 4; m++)
#pragma unroll
        for (int n = 0; n < 4; n++)
#pragma unroll
            for (int r = 0; r < 4; r++)
                C[(size_t)(bm + wy * 64 + m * 16 + l4 * 4 + r) * N + bn + wx * 64 + n * 16 + l15] =
                    acc[m][n][r];
}

// ---------------------------------------------------------------------------
// SuRoPE on q,k from fused qkv; fp16 out [H][L][96]; ATTN_SCALE folded into Q.
// ---------------------------------------------------------------------------
__global__ void rope_half(const float* __restrict__ qkv, const float* __restrict__ sf,
                          _Float16* __restrict__ Qh, _Float16* __restrict__ Kh,
                          float rope_scale, float attn_scale) {
    int idx = blockIdx.x * blockDim.x + threadIdx.x;  // 2*32*2048*96
    const int d = idx % 96;
    int r = idx / 96;
    const int l = r % 2048; r /= 2048;
    const int h = r % 32;
    const int which = r / 32;  // 0=q, 1=k
    const size_t base = (size_t)l * 9216 + (size_t)which * 3072 + h * 96;
    const float val = qkv[base + d];
    const int j = (d < 48) ? d : d - 48;
    const float e = (float)(2 * j) / 96.0f;
    const float inv = 1.0f / (sf[j] * powf(10000.0f, e));
    const float ang = (float)l * inv;
    const float cv = cosf(ang) * rope_scale;
    const float sv = sinf(ang) * rope_scale;
    const float pair = qkv[base + ((d < 48) ? d + 48 : d - 48)];
    const float rot = (d < 48) ? -pair : pair;
    float out = val * cv + rot * sv;
    if (which == 0) out *= attn_scale;
    const size_t dst = ((size_t)h * 2048 + l) * 96 + d;
    if (which == 0) Qh[dst] = (_Float16)out;
    else            Kh[dst] = (_Float16)out;
}

// ---------------------------------------------------------------------------
// V transpose: qkv v-part [l][h*96+d] -> Vt[h][d][l] fp16
// ---------------------------------------------------------------------------
__global__ __launch_bounds__(256) void vtrans(const float* __restrict__ qkv,
                                              _Float16* __restrict__ Vt) {
    __shared__ float tile[64][100];
    const int h = blockIdx.y;
    const int l0 = blockIdx.x * 64;
    const int t = threadIdx.x;
#pragma unroll
    for (int i = 0; i < 6; i++) {
        const int v = t + i * 256;
        const int row = v / 24, seg = v % 24;
        *(f4*)&tile[row][seg * 4] =
            *(const f4*)(qkv + (size_t)(l0 + row) * 9216 + 6144 + h * 96 + seg * 4);
    }
    __syncthreads();
#pragma unroll
    for (int i = 0; i < 3; i++) {
        const int v = t + i * 256;
        const int d = v >> 3, lc = v & 7;
        h8 o;
#pragma unroll
        for (int j = 0; j < 8; j++) o[j] = (_Float16)tile[lc * 8 + j][d];
        *(h8*)(Vt + ((size_t)h * 96 + d) * 2048 + l0 + lc * 8) = o;
    }
}

// ---------------------------------------------------------------------------
// Flash attention, fp16 MFMA. Block = (64 q-rows, head), 4 waves x 16 rows.
// K/V double-buffered with async reg-staging; one barrier per KV tile.
// ---------------------------------------------------------------------------
__global__ __launch_bounds__(256, 2) void attn_mfma(
    const _Float16* __restrict__ Qh, const _Float16* __restrict__ Kh,
    const _Float16* __restrict__ Vt, _Float16* __restrict__ Oh) {
    __shared__ _Float16 Ks[2][64][104];
    __shared__ _Float16 Vs[2][96][72];
    __shared__ _Float16 Ps[4][16][72];

    const int h = blockIdx.y;
    const int qt = (int)gridDim.x - 1 - (int)blockIdx.x;  // heavy blocks first
    const int q0 = qt * 64;
    const int t = threadIdx.x, lane = t & 63, w = t >> 6;
    const int l15 = lane & 15, l4 = lane >> 4;

    const _Float16* Kg = Kh + (size_t)h * 2048 * 96;
    const _Float16* Vg = Vt + (size_t)h * 96 * 2048;

    h8 qf[3];
    const size_t qrow = ((size_t)h * 2048 + q0 + w * 16 + l15) * 96;
#pragma unroll
    for (int kc = 0; kc < 3; kc++) qf[kc] = ld8h(Qh + qrow + kc * 32 + l4 * 8);

    us8 kreg[3], vreg[3];
#pragma unroll
    for (int i = 0; i < 3; i++) {
        const int c = t + i * 256;
        kreg[i] = *(const us8*)(Kg + (size_t)(c / 12) * 96 + (c % 12) * 8);
        vreg[i] = *(const us8*)(Vg + (size_t)(c >> 3) * 2048 + (c & 7) * 8);
    }

    f32x4 o[6] = {};
    float m_i[4] = {-1e30f, -1e30f, -1e30f, -1e30f};
    float l_i[4] = {0.f, 0.f, 0.f, 0.f};

    for (int kt = 0; kt <= qt; kt++) {
        const int buf = kt & 1;
#pragma unroll
        for (int i = 0; i < 3; i++) {
            const int c = t + i * 256;
            *(us8*)&Ks[buf][c / 12][(c % 12) * 8] = kreg[i];
            *(us8*)&Vs[buf][c >> 3][(c & 7) * 8] = vreg[i];
        }
        __syncthreads();
        if (kt < qt) {
            const int kv1 = (kt + 1) * 64;
#pragma unroll
            for (int i = 0; i < 3; i++) {
                const int c = t + i * 256;
                kreg[i] = *(const us8*)(Kg + (size_t)(kv1 + c / 12) * 96 + (c % 12) * 8);
                vreg[i] = *(const us8*)(Vg + (size_t)(c >> 3) * 2048 + kv1 + (c & 7) * 8);
            }
        }

        // S = Q K^T
        f32x4 s[4] = {};
#pragma unroll
        for (int f = 0; f < 4; f++)
#pragma unroll
            for (int kc = 0; kc < 3; kc++) {
                h8 kf = ld8h(&Ks[buf][f * 16 + l15][kc * 32 + l4 * 8]);
                s[f] = __builtin_amdgcn_mfma_f32_16x16x32_f16(qf[kc], kf, s[f], 0, 0, 0);
            }

        if (kt == qt) {
#pragma unroll
            for (int f = 0; f < 4; f++)
#pragma unroll
                for (int r = 0; r < 4; r++)
                    if (f * 16 + l15 > w * 16 + l4 * 4 + r) s[f][r] = -1e30f;
        }

        float pr[4][4], sc[4];
#pragma unroll
        for (int r = 0; r < 4; r++) {
            float mx = fmaxf(fmaxf(s[0][r], s[1][r]), fmaxf(s[2][r], s[3][r]));
#pragma unroll
            for (int msk = 1; msk < 16; msk <<= 1) mx = fmaxf(mx, __shfl_xor(mx, msk, 64));
            const float mnew = fmaxf(m_i[r], mx);
            sc[r] = __expf(m_i[r] - mnew);
            m_i[r] = mnew;
            float ssum = 0.f;
#pragma unroll
            for (int f = 0; f < 4; f++) {
                const float p = __expf(s[f][r] - mnew);
                pr[f][r] = p;
                ssum += p;
            }
#pragma unroll
            for (int msk = 1; msk < 16; msk <<= 1) ssum += __shfl_xor(ssum, msk, 64);
            l_i[r] = l_i[r] * sc[r] + ssum;
        }
#pragma unroll
        for (int f2 = 0; f2 < 6; f2++)
#pragma unroll
            for (int r = 0; r < 4; r++) o[f2][r] *= sc[r];

#pragma unroll
        for (int f = 0; f < 4; f++)
#pragma unroll
            for (int r = 0; r < 4; r++)
                Ps[w][l4 * 4 + r][f * 16 + l15] = (_Float16)pr[f][r];

#pragma unroll
        for (int kc2 = 0; kc2 < 2; kc2++) {
            h8 pa = ld8h(&Ps[w][l15][kc2 * 32 + l4 * 8]);
#pragma unroll
            for (int f2 = 0; f2 < 6; f2++) {
                h8 vb = ld8h(&Vs[buf][f2 * 16 + l15][kc2 * 32 + l4 * 8]);
                o[f2] = __builtin_amdgcn_mfma_f32_16x16x32_f16(pa, vb, o[f2], 0, 0, 0);
            }
        }
    }

#pragma unroll
    for (int r = 0; r < 4; r++) {
        const float inv = 1.0f / l_i[r];
        const size_t row = (size_t)(q0 + w * 16 + l4 * 4 + r) * 3072 + h * 96;
#pragma unroll
        for (int f2 = 0; f2 < 6; f2++)
            Oh[row + f2 * 16 + l15] = (_Float16)(o[f2][r] * inv);
    }
}

// ---------------------------------------------------------------------------
extern "C" void kernel_launch(void* const* d_in, const int* in_sizes, int n_in,
                              void* d_out, int out_size, void* d_ws, size_t ws_size,
                              hipStream_t stream) {
    const float* x = (const float*)d_in[0];
    const float* w_qkv = (const float*)d_in[1];
    const float* w_o = (const float*)d_in[2];
    const float* sf = (const float*)d_in[3];
    float* out = (float*)d_out;
    char* ws = (char*)d_ws;

    _Float16* wqkvh = (_Float16*)(ws);
    _Float16* Qh = (_Float16*)(ws);
    _Float16* Kh = (_Float16*)(ws + 12582912);
    _Float16* Vth = (_Float16*)(ws + 25165824);
    _Float16* Oh = (_Float16*)(ws + 37748736);
    float* qkv = (float*)(ws + 56623104);
    _Float16* xh = (_Float16*)(ws + 132120576);
    _Float16* woh = (_Float16*)(ws + 144703488);

    const float rope_scale = (float)sqrt(1.0 + log(131072.0 / 4096.0) / log(4096.0));
    const float attn_scale = (float)(1.0 / sqrt(96.0));

    convert_half<<<3072, 256, 0, stream>>>(x, xh, 786432);
    convert_half<<<13824, 256, 0, stream>>>(w_qkv, wqkvh, 3538944);
    gemm256<<<dim3(36, 8), 512, 0, stream>>>(xh, wqkvh, qkv, 2048, 9216, 3072);
    rope_half<<<49152, 256, 0, stream>>>(qkv, sf, Qh, Kh, rope_scale, attn_scale);
    vtrans<<<dim3(32, 32), 256, 0, stream>>>(qkv, Vth);
    convert_half<<<4608, 256, 0, stream>>>(w_o, woh, 1179648);
    attn_mfma<<<dim3(32, 32), 256, 0, stream>>>(Qh, Kh, Vth, Oh);
    gemm_fp16<<<dim3(24, 16), 256, 0, stream>>>(Oh, woh, out, 2048, 3072, 3072);
}

// Round 9
// 472.838 us; speedup vs baseline: 1.1829x; 1.1829x over previous
//
#include <hip/hip_runtime.h>
#include <math.h>

typedef __attribute__((ext_vector_type(4))) float f32x4;
typedef __attribute__((ext_vector_type(4))) float f4;
typedef __attribute__((ext_vector_type(8))) _Float16 h8;
typedef __attribute__((ext_vector_type(8))) unsigned short us8;

static __device__ __forceinline__ h8 ld8h(const _Float16* p) {
    return __builtin_bit_cast(h8, *(const us8*)p);
}
static __device__ __forceinline__ void glds16(const void* g, void* l) {
    __builtin_amdgcn_global_load_lds((const __attribute__((address_space(1))) unsigned int*)g,
                                     (__attribute__((address_space(3))) unsigned int*)l, 16, 0, 0);
}

// ---------------------------------------------------------------------------
// fp32 -> fp16, 8 elements/thread
// ---------------------------------------------------------------------------
__global__ void convert_half(const float* __restrict__ in, _Float16* __restrict__ out, int n8) {
    int i = blockIdx.x * blockDim.x + threadIdx.x;
    if (i >= n8) return;
    f4 v0 = *(const f4*)(in + (size_t)i * 8);
    f4 v1 = *(const f4*)(in + (size_t)i * 8 + 4);
    h8 o;
#pragma unroll
    for (int j = 0; j < 4; j++) {
        o[j] = (_Float16)v0[j];
        o[j + 4] = (_Float16)v1[j];
    }
    *(h8*)(out + (size_t)i * 8) = o;
}

// ---------------------------------------------------------------------------
// C = A @ B^T fp16 MFMA, templated output type. 128x128, BK=32, dbuf,
// 0-conflict XOR swizzle (HW-verified R6), 3 blocks/CU.
// ---------------------------------------------------------------------------
template <typename OT>
__global__ __launch_bounds__(256, 3) void gemm_t(
    const _Float16* __restrict__ A, const _Float16* __restrict__ B,
    OT* __restrict__ C, int M, int N, int K) {
    __shared__ _Float16 As[2][128][32], Bs[2][128][32];
    const int t = threadIdx.x;
    const int lane = t & 63, w = t >> 6;
    const int bm = blockIdx.y * 128, bn = blockIdx.x * 128;
    const int wy = w >> 1, wx = w & 1;
    const int l15 = lane & 15, l4 = lane >> 4;

    const int c0 = (w * 2 + 0) * 64 + lane;
    const int c1 = (w * 2 + 1) * 64 + lane;
    const int r0s = c0 >> 2, s0 = (((c0 & 3) ^ ((r0s >> 1) & 3)) * 8);
    const int r1s = c1 >> 2, s1 = (((c1 & 3) ^ ((r1s >> 1) & 3)) * 8);

    f32x4 acc[4][4] = {};

    glds16(A + (size_t)(bm + r0s) * K + s0, &As[0][0][0] + c0 * 8);
    glds16(A + (size_t)(bm + r1s) * K + s1, &As[0][0][0] + c1 * 8);
    glds16(B + (size_t)(bn + r0s) * K + s0, &Bs[0][0][0] + c0 * 8);
    glds16(B + (size_t)(bn + r1s) * K + s1, &Bs[0][0][0] + c1 * 8);

    int cry[4], crx[4];
#pragma unroll
    for (int m = 0; m < 4; m++) {
        const int rowA = wy * 64 + m * 16 + l15;
        cry[m] = ((l4 ^ ((rowA >> 1) & 3)) * 8);
        const int rowB = wx * 64 + m * 16 + l15;
        crx[m] = ((l4 ^ ((rowB >> 1) & 3)) * 8);
    }

    int cur = 0;
    for (int k0 = 0; k0 < K; k0 += 32) {
        __syncthreads();
        const int nk = k0 + 32;
        if (nk < K) {
            _Float16* an = &As[cur ^ 1][0][0];
            _Float16* bn_ = &Bs[cur ^ 1][0][0];
            glds16(A + (size_t)(bm + r0s) * K + nk + s0, an + c0 * 8);
            glds16(A + (size_t)(bm + r1s) * K + nk + s1, an + c1 * 8);
            glds16(B + (size_t)(bn + r0s) * K + nk + s0, bn_ + c0 * 8);
            glds16(B + (size_t)(bn + r1s) * K + nk + s1, bn_ + c1 * 8);
        }
        h8 af[4], bf[4];
#pragma unroll
        for (int m = 0; m < 4; m++) af[m] = ld8h(&As[cur][wy * 64 + m * 16 + l15][cry[m]]);
#pragma unroll
        for (int n = 0; n < 4; n++) bf[n] = ld8h(&Bs[cur][wx * 64 + n * 16 + l15][crx[n]]);
#pragma unroll
        for (int m = 0; m < 4; m++)
#pragma unroll
            for (int n = 0; n < 4; n++)
                acc[m][n] = __builtin_amdgcn_mfma_f32_16x16x32_f16(af[m], bf[n], acc[m][n], 0, 0, 0);
        cur ^= 1;
    }

#pragma unroll
    for (int m = 0; m < 4; m++)
#pragma unroll
        for (int n = 0; n < 4; n++)
#pragma unroll
            for (int r = 0; r < 4; r++)
                C[(size_t)(bm + wy * 64 + m * 16 + l4 * 4 + r) * N + bn + wx * 64 + n * 16 + l15] =
                    (OT)acc[m][n][r];
}

// ---------------------------------------------------------------------------
// SuRoPE on q,k from fp16 qkv; fp16 out [H][L][96]; ATTN_SCALE folded into Q.
// ---------------------------------------------------------------------------
__global__ void rope_half(const _Float16* __restrict__ qkv, const float* __restrict__ sf,
                          _Float16* __restrict__ Qh, _Float16* __restrict__ Kh,
                          float rope_scale, float attn_scale) {
    int idx = blockIdx.x * blockDim.x + threadIdx.x;  // 2*32*2048*96
    const int d = idx % 96;
    int r = idx / 96;
    const int l = r % 2048; r /= 2048;
    const int h = r % 32;
    const int which = r / 32;  // 0=q, 1=k
    const size_t base = (size_t)l * 9216 + (size_t)which * 3072 + h * 96;
    const float val = (float)qkv[base + d];
    const int j = (d < 48) ? d : d - 48;
    const float e = (float)(2 * j) / 96.0f;
    const float inv = 1.0f / (sf[j] * powf(10000.0f, e));
    const float ang = (float)l * inv;
    const float cv = cosf(ang) * rope_scale;
    const float sv = sinf(ang) * rope_scale;
    const float pair = (float)qkv[base + ((d < 48) ? d + 48 : d - 48)];
    const float rot = (d < 48) ? -pair : pair;
    float out = val * cv + rot * sv;
    if (which == 0) out *= attn_scale;
    const size_t dst = ((size_t)h * 2048 + l) * 96 + d;
    if (which == 0) Qh[dst] = (_Float16)out;
    else            Kh[dst] = (_Float16)out;
}

// ---------------------------------------------------------------------------
// V transpose: fp16 qkv v-part [l][h*96+d] -> Vt[h][d][l] fp16. Pad 105
// breaks the 8-way column-read conflict of the old pad-100 version.
// ---------------------------------------------------------------------------
__global__ __launch_bounds__(256) void vtrans(const _Float16* __restrict__ qkv,
                                              _Float16* __restrict__ Vt) {
    __shared__ _Float16 tile[64][105];
    const int h = blockIdx.y;
    const int l0 = blockIdx.x * 64;
    const int t = threadIdx.x;
#pragma unroll
    for (int i = 0; i < 3; i++) {
        const int v = t + i * 256;
        const int row = v / 12, seg = (v % 12) * 8;
        *(us8*)&tile[row][seg] =
            *(const us8*)(qkv + (size_t)(l0 + row) * 9216 + 6144 + h * 96 + seg);
    }
    __syncthreads();
#pragma unroll
    for (int i = 0; i < 3; i++) {
        const int v = t + i * 256;
        const int d = v >> 3, lc = v & 7;
        h8 o;
#pragma unroll
        for (int j = 0; j < 8; j++) o[j] = tile[lc * 8 + j][d];
        *(h8*)(Vt + ((size_t)h * 96 + d) * 2048 + l0 + lc * 8) = o;
    }
}

// ---------------------------------------------------------------------------
// Flash attention, fp16 MFMA. Block = (128 q-rows, head) = 8 waves x 16 rows,
// 512 threads, grid 16x32 = 512 blocks = exactly 2/CU. KV tiles of 64,
// dbuf + async reg-staging, one barrier per tile. Waves skip fully-masked
// tiles (compute only; barriers/staging kept).
// ---------------------------------------------------------------------------
__global__ __launch_bounds__(512, 4) void attn_mfma(
    const _Float16* __restrict__ Qh, const _Float16* __restrict__ Kh,
    const _Float16* __restrict__ Vt, _Float16* __restrict__ Oh) {
    __shared__ _Float16 Ks[2][64][104];
    __shared__ _Float16 Vs[2][96][72];
    __shared__ _Float16 Ps[8][16][72];

    const int h = blockIdx.y;
    const int qt = 15 - (int)blockIdx.x;  // heavy blocks first
    const int q0 = qt * 128;
    const int t = threadIdx.x, lane = t & 63, w = t >> 6;
    const int l15 = lane & 15, l4 = lane >> 4;
    const int wq = q0 + w * 16;  // this wave's first q-row

    const _Float16* Kg = Kh + (size_t)h * 2048 * 96;
    const _Float16* Vg = Vt + (size_t)h * 96 * 2048;

    h8 qf[3];
    const size_t qrow = ((size_t)h * 2048 + wq + l15) * 96;
#pragma unroll
    for (int kc = 0; kc < 3; kc++) qf[kc] = ld8h(Qh + qrow + kc * 32 + l4 * 8);

    // staging: K tile 64x96 = 768 us8-chunks; V tile 96x64 = 768 chunks.
    // chunk cA = t (all threads), chunk cB = 512+t (threads t<256 only).
    const int cA = t, rKA = cA / 12, sKA = (cA % 12) * 8;
    const int rVA = cA >> 3, sVA = (cA & 7) * 8;
    const int cB = 512 + t, rKB = cB / 12, sKB = (cB % 12) * 8;
    const int rVB = cB >> 3, sVB = (cB & 7) * 8;
    const bool two = (t < 256);

    us8 kregA, vregA, kregB, vregB;
    kregA = *(const us8*)(Kg + (size_t)rKA * 96 + sKA);
    vregA = *(const us8*)(Vg + (size_t)rVA * 2048 + sVA);
    if (two) {
        kregB = *(const us8*)(Kg + (size_t)rKB * 96 + sKB);
        vregB = *(const us8*)(Vg + (size_t)rVB * 2048 + sVB);
    }

    f32x4 o[6] = {};
    float m_i[4] = {-1e30f, -1e30f, -1e30f, -1e30f};
    float l_i[4] = {0.f, 0.f, 0.f, 0.f};

    const int nkt = 2 * qt + 2;
    for (int kt = 0; kt < nkt; kt++) {
        const int kv0 = kt * 64;
        const int buf = kt & 1;
        *(us8*)&Ks[buf][rKA][sKA] = kregA;
        *(us8*)&Vs[buf][rVA][sVA] = vregA;
        if (two) {
            *(us8*)&Ks[buf][rKB][sKB] = kregB;
            *(us8*)&Vs[buf][rVB][sVB] = vregB;
        }
        __syncthreads();
        if (kt + 1 < nkt) {
            const int kv1 = kv0 + 64;
            kregA = *(const us8*)(Kg + (size_t)(kv1 + rKA) * 96 + sKA);
            vregA = *(const us8*)(Vg + (size_t)rVA * 2048 + kv1 + sVA);
            if (two) {
                kregB = *(const us8*)(Kg + (size_t)(kv1 + rKB) * 96 + sKB);
                vregB = *(const us8*)(Vg + (size_t)rVB * 2048 + kv1 + sVB);
            }
        }

        if (kv0 <= wq + 15) {  // tile visible to at least one of this wave's rows
            // S = Q K^T
            f32x4 s[4] = {};
#pragma unroll
            for (int f = 0; f < 4; f++)
#pragma unroll
                for (int kc = 0; kc < 3; kc++) {
                    h8 kf = ld8h(&Ks[buf][f * 16 + l15][kc * 32 + l4 * 8]);
                    s[f] = __builtin_amdgcn_mfma_f32_16x16x32_f16(qf[kc], kf, s[f], 0, 0, 0);
                }

            if (kv0 + 63 > wq) {  // diagonal-crossing: elementwise causal mask
#pragma unroll
                for (int f = 0; f < 4; f++)
#pragma unroll
                    for (int r = 0; r < 4; r++)
                        if (kv0 + f * 16 + l15 > wq + l4 * 4 + r) s[f][r] = -1e30f;
            }

            float pr[4][4], sc[4];
#pragma unroll
            for (int r = 0; r < 4; r++) {
                float mx = fmaxf(fmaxf(s[0][r], s[1][r]), fmaxf(s[2][r], s[3][r]));
#pragma unroll
                for (int msk = 1; msk < 16; msk <<= 1) mx = fmaxf(mx, __shfl_xor(mx, msk, 64));
                const float mnew = fmaxf(m_i[r], mx);
                sc[r] = __expf(m_i[r] - mnew);
                m_i[r] = mnew;
                float ssum = 0.f;
#pragma unroll
                for (int f = 0; f < 4; f++) {
                    const float p = __expf(s[f][r] - mnew);
                    pr[f][r] = p;
                    ssum += p;
                }
#pragma unroll
                for (int msk = 1; msk < 16; msk <<= 1) ssum += __shfl_xor(ssum, msk, 64);
                l_i[r] = l_i[r] * sc[r] + ssum;
            }
#pragma unroll
            for (int f2 = 0; f2 < 6; f2++)
#pragma unroll
                for (int r = 0; r < 4; r++) o[f2][r] *= sc[r];

#pragma unroll
            for (int f = 0; f < 4; f++)
#pragma unroll
                for (int r = 0; r < 4; r++)
                    Ps[w][l4 * 4 + r][f * 16 + l15] = (_Float16)pr[f][r];

#pragma unroll
            for (int kc2 = 0; kc2 < 2; kc2++) {
                h8 pa = ld8h(&Ps[w][l15][kc2 * 32 + l4 * 8]);
#pragma unroll
                for (int f2 = 0; f2 < 6; f2++) {
                    h8 vb = ld8h(&Vs[buf][f2 * 16 + l15][kc2 * 32 + l4 * 8]);
                    o[f2] = __builtin_amdgcn_mfma_f32_16x16x32_f16(pa, vb, o[f2], 0, 0, 0);
                }
            }
        }
    }

#pragma unroll
    for (int r = 0; r < 4; r++) {
        const float inv = 1.0f / l_i[r];
        const size_t row = (size_t)(wq + l4 * 4 + r) * 3072 + h * 96;
#pragma unroll
        for (int f2 = 0; f2 < 6; f2++)
            Oh[row + f2 * 16 + l15] = (_Float16)(o[f2][r] * inv);
    }
}

// ---------------------------------------------------------------------------
extern "C" void kernel_launch(void* const* d_in, const int* in_sizes, int n_in,
                              void* d_out, int out_size, void* d_ws, size_t ws_size,
                              hipStream_t stream) {
    const float* x = (const float*)d_in[0];
    const float* w_qkv = (const float*)d_in[1];
    const float* w_o = (const float*)d_in[2];
    const float* sf = (const float*)d_in[3];
    float* out = (float*)d_out;
    char* ws = (char*)d_ws;

    _Float16* wqkvh = (_Float16*)(ws);            // [0, 56.6MB) dead after GEMM1
    _Float16* Qh = (_Float16*)(ws);
    _Float16* Kh = (_Float16*)(ws + 12582912);
    _Float16* Vth = (_Float16*)(ws + 25165824);
    _Float16* Oh = (_Float16*)(ws + 37748736);
    _Float16* qkvh = (_Float16*)(ws + 56623104);  // fp16 qkv, 37.7MB
    _Float16* xh = (_Float16*)(ws + 132120576);
    _Float16* woh = (_Float16*)(ws + 144703488);

    const float rope_scale = (float)sqrt(1.0 + log(131072.0 / 4096.0) / log(4096.0));
    const float attn_scale = (float)(1.0 / sqrt(96.0));

    convert_half<<<3072, 256, 0, stream>>>(x, xh, 786432);
    convert_half<<<13824, 256, 0, stream>>>(w_qkv, wqkvh, 3538944);
    gemm_t<_Float16><<<dim3(72, 16), 256, 0, stream>>>(xh, wqkvh, qkvh, 2048, 9216, 3072);
    rope_half<<<49152, 256, 0, stream>>>(qkvh, sf, Qh, Kh, rope_scale, attn_scale);
    vtrans<<<dim3(32, 32), 256, 0, stream>>>(qkvh, Vth);
    convert_half<<<4608, 256, 0, stream>>>(w_o, woh, 1179648);
    attn_mfma<<<dim3(16, 32), 512, 0, stream>>>(Qh, Kh, Vth, Oh);
    gemm_t<float><<<dim3(24, 16), 256, 0, stream>>>(Oh, woh, out, 2048, 3072, 3072);
}

// Round 10
// 468.245 us; speedup vs baseline: 1.1945x; 1.0098x over previous
//
#include <hip/hip_runtime.h>
#include <math.h>

typedef __attribute__((ext_vector_type(4))) float f32x4;
typedef __attribute__((ext_vector_type(4))) float f4;
typedef __attribute__((ext_vector_type(8))) _Float16 h8;
typedef __attribute__((ext_vector_type(8))) unsigned short us8;

static __device__ __forceinline__ h8 ld8h(const _Float16* p) {
    return __builtin_bit_cast(h8, *(const us8*)p);
}
static __device__ __forceinline__ void glds16(const void* g, void* l) {
    __builtin_amdgcn_global_load_lds((const __attribute__((address_space(1))) unsigned int*)g,
                                     (__attribute__((address_space(3))) unsigned int*)l, 16, 0, 0);
}

// ---------------------------------------------------------------------------
// fp32 -> fp16, 8 elements/thread
// ---------------------------------------------------------------------------
__global__ void convert_half(const float* __restrict__ in, _Float16* __restrict__ out, int n8) {
    int i = blockIdx.x * blockDim.x + threadIdx.x;
    if (i >= n8) return;
    f4 v0 = *(const f4*)(in + (size_t)i * 8);
    f4 v1 = *(const f4*)(in + (size_t)i * 8 + 4);
    h8 o;
#pragma unroll
    for (int j = 0; j < 4; j++) {
        o[j] = (_Float16)v0[j];
        o[j + 4] = (_Float16)v1[j];
    }
    *(h8*)(out + (size_t)i * 8) = o;
}

// ---------------------------------------------------------------------------
// C = A @ B^T fp16 MFMA, templated output. 128x128, BK=32, dbuf,
// 0-conflict XOR swizzle, 3 blocks/CU. (Plateau kernel: 624 TF, MfmaUtil 27%.)
// ---------------------------------------------------------------------------
template <typename OT>
__global__ __launch_bounds__(256, 3) void gemm_t(
    const _Float16* __restrict__ A, const _Float16* __restrict__ B,
    OT* __restrict__ C, int M, int N, int K) {
    __shared__ _Float16 As[2][128][32], Bs[2][128][32];
    const int t = threadIdx.x;
    const int lane = t & 63, w = t >> 6;
    const int bm = blockIdx.y * 128, bn = blockIdx.x * 128;
    const int wy = w >> 1, wx = w & 1;
    const int l15 = lane & 15, l4 = lane >> 4;

    const int c0 = (w * 2 + 0) * 64 + lane;
    const int c1 = (w * 2 + 1) * 64 + lane;
    const int r0s = c0 >> 2, s0 = (((c0 & 3) ^ ((r0s >> 1) & 3)) * 8);
    const int r1s = c1 >> 2, s1 = (((c1 & 3) ^ ((r1s >> 1) & 3)) * 8);

    f32x4 acc[4][4] = {};

    glds16(A + (size_t)(bm + r0s) * K + s0, &As[0][0][0] + c0 * 8);
    glds16(A + (size_t)(bm + r1s) * K + s1, &As[0][0][0] + c1 * 8);
    glds16(B + (size_t)(bn + r0s) * K + s0, &Bs[0][0][0] + c0 * 8);
    glds16(B + (size_t)(bn + r1s) * K + s1, &Bs[0][0][0] + c1 * 8);

    int cry[4], crx[4];
#pragma unroll
    for (int m = 0; m < 4; m++) {
        const int rowA = wy * 64 + m * 16 + l15;
        cry[m] = ((l4 ^ ((rowA >> 1) & 3)) * 8);
        const int rowB = wx * 64 + m * 16 + l15;
        crx[m] = ((l4 ^ ((rowB >> 1) & 3)) * 8);
    }

    int cur = 0;
    for (int k0 = 0; k0 < K; k0 += 32) {
        __syncthreads();
        const int nk = k0 + 32;
        if (nk < K) {
            _Float16* an = &As[cur ^ 1][0][0];
            _Float16* bn_ = &Bs[cur ^ 1][0][0];
            glds16(A + (size_t)(bm + r0s) * K + nk + s0, an + c0 * 8);
            glds16(A + (size_t)(bm + r1s) * K + nk + s1, an + c1 * 8);
            glds16(B + (size_t)(bn + r0s) * K + nk + s0, bn_ + c0 * 8);
            glds16(B + (size_t)(bn + r1s) * K + nk + s1, bn_ + c1 * 8);
        }
        h8 af[4], bf[4];
#pragma unroll
        for (int m = 0; m < 4; m++) af[m] = ld8h(&As[cur][wy * 64 + m * 16 + l15][cry[m]]);
#pragma unroll
        for (int n = 0; n < 4; n++) bf[n] = ld8h(&Bs[cur][wx * 64 + n * 16 + l15][crx[n]]);
#pragma unroll
        for (int m = 0; m < 4; m++)
#pragma unroll
            for (int n = 0; n < 4; n++)
                acc[m][n] = __builtin_amdgcn_mfma_f32_16x16x32_f16(af[m], bf[n], acc[m][n], 0, 0, 0);
        cur ^= 1;
    }

#pragma unroll
    for (int m = 0; m < 4; m++)
#pragma unroll
        for (int n = 0; n < 4; n++)
#pragma unroll
            for (int r = 0; r < 4; r++)
                C[(size_t)(bm + wy * 64 + m * 16 + l4 * 4 + r) * N + bn + wx * 64 + n * 16 + l15] =
                    (OT)acc[m][n][r];
}

// ---------------------------------------------------------------------------
// SuRoPE on q,k from fp16 qkv; fp16 out [H][L][96]; ATTN_SCALE folded into Q.
// ---------------------------------------------------------------------------
__global__ void rope_half(const _Float16* __restrict__ qkv, const float* __restrict__ sf,
                          _Float16* __restrict__ Qh, _Float16* __restrict__ Kh,
                          float rope_scale, float attn_scale) {
    int idx = blockIdx.x * blockDim.x + threadIdx.x;  // 2*32*2048*96
    const int d = idx % 96;
    int r = idx / 96;
    const int l = r % 2048; r /= 2048;
    const int h = r % 32;
    const int which = r / 32;  // 0=q, 1=k
    const size_t base = (size_t)l * 9216 + (size_t)which * 3072 + h * 96;
    const float val = (float)qkv[base + d];
    const int j = (d < 48) ? d : d - 48;
    const float e = (float)(2 * j) / 96.0f;
    const float inv = 1.0f / (sf[j] * powf(10000.0f, e));
    const float ang = (float)l * inv;
    const float cv = cosf(ang) * rope_scale;
    const float sv = sinf(ang) * rope_scale;
    const float pair = (float)qkv[base + ((d < 48) ? d + 48 : d - 48)];
    const float rot = (d < 48) ? -pair : pair;
    float out = val * cv + rot * sv;
    if (which == 0) out *= attn_scale;
    const size_t dst = ((size_t)h * 2048 + l) * 96 + d;
    if (which == 0) Qh[dst] = (_Float16)out;
    else            Kh[dst] = (_Float16)out;
}

// ---------------------------------------------------------------------------
// V transpose: fp16 qkv v-part [l][h*96+d] -> Vt[h][d][l] fp16.
// ---------------------------------------------------------------------------
__global__ __launch_bounds__(256) void vtrans(const _Float16* __restrict__ qkv,
                                              _Float16* __restrict__ Vt) {
    __shared__ _Float16 tile[64][105];
    const int h = blockIdx.y;
    const int l0 = blockIdx.x * 64;
    const int t = threadIdx.x;
#pragma unroll
    for (int i = 0; i < 3; i++) {
        const int v = t + i * 256;
        const int row = v / 12, seg = (v % 12) * 8;
        *(us8*)&tile[row][seg] =
            *(const us8*)(qkv + (size_t)(l0 + row) * 9216 + 6144 + h * 96 + seg);
    }
    __syncthreads();
#pragma unroll
    for (int i = 0; i < 3; i++) {
        const int v = t + i * 256;
        const int d = v >> 3, lc = v & 7;
        h8 o;
#pragma unroll
        for (int j = 0; j < 8; j++) o[j] = tile[lc * 8 + j][d];
        *(h8*)(Vt + ((size_t)h * 96 + d) * 2048 + l0 + lc * 8) = o;
    }
}

// ---------------------------------------------------------------------------
// Flash attention, fp16 MFMA. Block = (256 q-rows, head) = 8 waves x 32 rows
// (2 row-groups of 16), 512 threads, grid 8x32 = 256 blocks (1/CU).
// KV tiles of 64, dbuf + async reg-staging (T14), one barrier per tile.
// Defer-max (T13): skip O-rescale while tile max grows <= 8 (exact algebra).
// P LDS buffer per-wave, reused across the 2 row-groups (same-wave DS order).
// ---------------------------------------------------------------------------
__global__ __launch_bounds__(512, 2) void attn_mfma(
    const _Float16* __restrict__ Qh, const _Float16* __restrict__ Kh,
    const _Float16* __restrict__ Vt, _Float16* __restrict__ Oh) {
    __shared__ _Float16 Ks[2][64][104];
    __shared__ _Float16 Vs[2][96][72];
    __shared__ _Float16 Ps[8][16][72];

    const int h = blockIdx.y;
    const int qt = 7 - (int)blockIdx.x;  // heavy blocks first
    const int q0 = qt * 256;
    const int t = threadIdx.x, lane = t & 63, w = t >> 6;
    const int l15 = lane & 15, l4 = lane >> 4;
    const int wq = q0 + w * 32;  // this wave's first q-row (32 rows)

    const _Float16* Kg = Kh + (size_t)h * 2048 * 96;
    const _Float16* Vg = Vt + (size_t)h * 96 * 2048;

    h8 qf[2][3];
#pragma unroll
    for (int g = 0; g < 2; g++) {
        const size_t qrow = ((size_t)h * 2048 + wq + g * 16 + l15) * 96;
#pragma unroll
        for (int kc = 0; kc < 3; kc++) qf[g][kc] = ld8h(Qh + qrow + kc * 32 + l4 * 8);
    }

    // staging: K tile 64x96 = 768 chunks; V tile 96x64 = 768 chunks.
    const int cA = t, rKA = cA / 12, sKA = (cA % 12) * 8;
    const int rVA = cA >> 3, sVA = (cA & 7) * 8;
    const int cB = 512 + t, rKB = cB / 12, sKB = (cB % 12) * 8;
    const int rVB = cB >> 3, sVB = (cB & 7) * 8;
    const bool two = (t < 256);

    us8 kregA, vregA, kregB, vregB;
    kregA = *(const us8*)(Kg + (size_t)rKA * 96 + sKA);
    vregA = *(const us8*)(Vg + (size_t)rVA * 2048 + sVA);
    if (two) {
        kregB = *(const us8*)(Kg + (size_t)rKB * 96 + sKB);
        vregB = *(const us8*)(Vg + (size_t)rVB * 2048 + sVB);
    }

    f32x4 o[2][6] = {};
    float m_i[2][4], l_i[2][4];
#pragma unroll
    for (int g = 0; g < 2; g++)
#pragma unroll
        for (int r = 0; r < 4; r++) { m_i[g][r] = -1e30f; l_i[g][r] = 0.f; }

    const int nkt = 4 * qt + 4;
    for (int kt = 0; kt < nkt; kt++) {
        const int kv0 = kt * 64;
        const int buf = kt & 1;
        *(us8*)&Ks[buf][rKA][sKA] = kregA;
        *(us8*)&Vs[buf][rVA][sVA] = vregA;
        if (two) {
            *(us8*)&Ks[buf][rKB][sKB] = kregB;
            *(us8*)&Vs[buf][rVB][sVB] = vregB;
        }
        __syncthreads();
        if (kt + 1 < nkt) {  // issue next tile's loads; hide under compute
            const int kv1 = kv0 + 64;
            kregA = *(const us8*)(Kg + (size_t)(kv1 + rKA) * 96 + sKA);
            vregA = *(const us8*)(Vg + (size_t)rVA * 2048 + kv1 + sVA);
            if (two) {
                kregB = *(const us8*)(Kg + (size_t)(kv1 + rKB) * 96 + sKB);
                vregB = *(const us8*)(Vg + (size_t)rVB * 2048 + kv1 + sVB);
            }
        }

        if (kv0 <= wq + 31) {  // tile visible to this wave
            // S = Q K^T for both row-groups
            f32x4 s[2][4] = {};
#pragma unroll
            for (int f = 0; f < 4; f++)
#pragma unroll
                for (int kc = 0; kc < 3; kc++) {
                    h8 kf = ld8h(&Ks[buf][f * 16 + l15][kc * 32 + l4 * 8]);
#pragma unroll
                    for (int g = 0; g < 2; g++)
                        s[g][f] = __builtin_amdgcn_mfma_f32_16x16x32_f16(qf[g][kc], kf, s[g][f], 0, 0, 0);
                }

            if (kv0 + 63 > wq) {  // diagonal-crossing: elementwise causal mask
#pragma unroll
                for (int g = 0; g < 2; g++)
#pragma unroll
                    for (int f = 0; f < 4; f++)
#pragma unroll
                        for (int r = 0; r < 4; r++)
                            if (kv0 + f * 16 + l15 > wq + g * 16 + l4 * 4 + r) s[g][f][r] = -1e30f;
            }

            // row maxes (shfl over the 16-lane l15 groups)
            float mx[2][4];
#pragma unroll
            for (int g = 0; g < 2; g++)
#pragma unroll
                for (int r = 0; r < 4; r++) {
                    float m0 = fmaxf(fmaxf(s[g][0][r], s[g][1][r]), fmaxf(s[g][2][r], s[g][3][r]));
#pragma unroll
                    for (int msk = 1; msk < 16; msk <<= 1) m0 = fmaxf(m0, __shfl_xor(m0, msk, 64));
                    mx[g][r] = m0;
                }

            // defer-max (T13): rescale only when some row's max grew > 8
            bool need = false;
#pragma unroll
            for (int g = 0; g < 2; g++)
#pragma unroll
                for (int r = 0; r < 4; r++) need = need || (mx[g][r] > m_i[g][r] + 8.0f);
            if (__any(need)) {
#pragma unroll
                for (int g = 0; g < 2; g++)
#pragma unroll
                    for (int r = 0; r < 4; r++) {
                        const float mnew = fmaxf(m_i[g][r], mx[g][r]);
                        const float sc = __expf(m_i[g][r] - mnew);
                        m_i[g][r] = mnew;
                        l_i[g][r] *= sc;
#pragma unroll
                        for (int f2 = 0; f2 < 6; f2++) o[g][f2][r] *= sc;
                    }
            }

            // P = exp(S - m), store to per-wave LDS, PV MFMA (P buffer reused per g)
#pragma unroll
            for (int g = 0; g < 2; g++) {
                float ssum[4] = {0.f, 0.f, 0.f, 0.f};
#pragma unroll
                for (int f = 0; f < 4; f++)
#pragma unroll
                    for (int r = 0; r < 4; r++) {
                        const float p = __expf(s[g][f][r] - m_i[g][r]);
                        Ps[w][l4 * 4 + r][f * 16 + l15] = (_Float16)p;
                        ssum[r] += p;
                    }
#pragma unroll
                for (int r = 0; r < 4; r++) {
                    float ss = ssum[r];
#pragma unroll
                    for (int msk = 1; msk < 16; msk <<= 1) ss += __shfl_xor(ss, msk, 64);
                    l_i[g][r] += ss;
                }
#pragma unroll
                for (int kc2 = 0; kc2 < 2; kc2++) {
                    h8 pa = ld8h(&Ps[w][l15][kc2 * 32 + l4 * 8]);
#pragma unroll
                    for (int f2 = 0; f2 < 6; f2++) {
                        h8 vb = ld8h(&Vs[buf][f2 * 16 + l15][kc2 * 32 + l4 * 8]);
                        o[g][f2] = __builtin_amdgcn_mfma_f32_16x16x32_f16(pa, vb, o[g][f2], 0, 0, 0);
                    }
                }
            }
        }
    }

    // epilogue: normalize, write fp16 O [L][3072]
#pragma unroll
    for (int g = 0; g < 2; g++)
#pragma unroll
        for (int r = 0; r < 4; r++) {
            const float inv = 1.0f / l_i[g][r];
            const size_t row = (size_t)(wq + g * 16 + l4 * 4 + r) * 3072 + h * 96;
#pragma unroll
            for (int f2 = 0; f2 < 6; f2++)
                Oh[row + f2 * 16 + l15] = (_Float16)(o[g][f2][r] * inv);
        }
}

// ---------------------------------------------------------------------------
extern "C" void kernel_launch(void* const* d_in, const int* in_sizes, int n_in,
                              void* d_out, int out_size, void* d_ws, size_t ws_size,
                              hipStream_t stream) {
    const float* x = (const float*)d_in[0];
    const float* w_qkv = (const float*)d_in[1];
    const float* w_o = (const float*)d_in[2];
    const float* sf = (const float*)d_in[3];
    float* out = (float*)d_out;
    char* ws = (char*)d_ws;

    _Float16* wqkvh = (_Float16*)(ws);            // [0, 56.6MB) dead after GEMM1
    _Float16* Qh = (_Float16*)(ws);
    _Float16* Kh = (_Float16*)(ws + 12582912);
    _Float16* Vth = (_Float16*)(ws + 25165824);
    _Float16* Oh = (_Float16*)(ws + 37748736);
    _Float16* qkvh = (_Float16*)(ws + 56623104);  // fp16 qkv, 37.7MB
    _Float16* xh = (_Float16*)(ws + 132120576);
    _Float16* woh = (_Float16*)(ws + 144703488);

    const float rope_scale = (float)sqrt(1.0 + log(131072.0 / 4096.0) / log(4096.0));
    const float attn_scale = (float)(1.0 / sqrt(96.0));

    convert_half<<<3072, 256, 0, stream>>>(x, xh, 786432);
    convert_half<<<13824, 256, 0, stream>>>(w_qkv, wqkvh, 3538944);
    gemm_t<_Float16><<<dim3(72, 16), 256, 0, stream>>>(xh, wqkvh, qkvh, 2048, 9216, 3072);
    rope_half<<<49152, 256, 0, stream>>>(qkvh, sf, Qh, Kh, rope_scale, attn_scale);
    vtrans<<<dim3(32, 32), 256, 0, stream>>>(qkvh, Vth);
    convert_half<<<4608, 256, 0, stream>>>(w_o, woh, 1179648);
    attn_mfma<<<dim3(8, 32), 512, 0, stream>>>(Qh, Kh, Vth, Oh);
    gemm_t<float><<<dim3(24, 16), 256, 0, stream>>>(Oh, woh, out, 2048, 3072, 3072);
}

// Round 11
// 341.064 us; speedup vs baseline: 1.6399x; 1.3729x over previous
//
#include <hip/hip_runtime.h>
#include <math.h>

typedef __attribute__((ext_vector_type(4))) float f32x4;
typedef __attribute__((ext_vector_type(4))) float f4;
typedef __attribute__((ext_vector_type(8))) _Float16 h8;
typedef __attribute__((ext_vector_type(8))) unsigned short us8;

static __device__ __forceinline__ h8 ld8h(const _Float16* p) {
    return __builtin_bit_cast(h8, *(const us8*)p);
}
static __device__ __forceinline__ void glds16(const void* g, void* l) {
    __builtin_amdgcn_global_load_lds((const __attribute__((address_space(1))) unsigned int*)g,
                                     (__attribute__((address_space(3))) unsigned int*)l, 16, 0, 0);
}

// ---------------------------------------------------------------------------
// fp32 -> fp16, 8 elements/thread
// ---------------------------------------------------------------------------
__global__ void convert_half(const float* __restrict__ in, _Float16* __restrict__ out, int n8) {
    int i = blockIdx.x * blockDim.x + threadIdx.x;
    if (i >= n8) return;
    f4 v0 = *(const f4*)(in + (size_t)i * 8);
    f4 v1 = *(const f4*)(in + (size_t)i * 8 + 4);
    h8 o;
#pragma unroll
    for (int j = 0; j < 4; j++) {
        o[j] = (_Float16)v0[j];
        o[j + 4] = (_Float16)v1[j];
    }
    *(h8*)(out + (size_t)i * 8) = o;
}

// ---------------------------------------------------------------------------
// SuRoPE cos/sin table: cs/sn[l][j] = cos/sin(l*inv_freq(j)) * rope_scale
// ---------------------------------------------------------------------------
__global__ void rope_table(const float* __restrict__ sf, float* __restrict__ cs,
                           float* __restrict__ sn, float rope_scale) {
    int i = blockIdx.x * blockDim.x + threadIdx.x;  // 2048*48
    const int j = i % 48, l = i / 48;
    const float e = (float)(2 * j) / 96.0f;
    const float inv = 1.0f / (sf[j] * powf(10000.0f, e));
    const float ang = (float)l * inv;
    cs[i] = cosf(ang) * rope_scale;
    sn[i] = sinf(ang) * rope_scale;
}

// ---------------------------------------------------------------------------
// QKV GEMM with fused SuRoPE + head-split epilogue.
// C = x @ w_qkv^T. BM=128, BN=192 (2x2 waves, per-wave 64x96 = one head's
// dims for 64 rows). Grid 48x16 = 768 blocks = EXACTLY 3/CU * 256 CUs.
// Rope pair (d, d+48) = frags (n, n+3): same lane, no cross-lane traffic.
// q/k/v boundaries (3072,6144) are multiples of 192 -> block-uniform 'which'.
// Outputs: Qh/Kh [h][l][96] (rope'd; Q scaled), Vh [h][l][96] plain.
// ---------------------------------------------------------------------------
__global__ __launch_bounds__(256, 3) void gemm_qkv(
    const _Float16* __restrict__ A, const _Float16* __restrict__ B,
    const float* __restrict__ cs, const float* __restrict__ sn,
    _Float16* __restrict__ Qh, _Float16* __restrict__ Kh, _Float16* __restrict__ Vh,
    float attn_scale) {
    const int K = 3072;
    __shared__ _Float16 As[2][128][32], Bs[2][192][32];
    const int t = threadIdx.x;
    const int lane = t & 63, w = t >> 6;
    const int bm = blockIdx.y * 128, bn = blockIdx.x * 192;
    const int wm = w >> 1, wn = w & 1;
    const int l15 = lane & 15, l4 = lane >> 4;

    // staging: A 512 chunks (2/thr), B 768 chunks (3/thr); inverse swizzle on src
    int car[2], cas[2], cbr[3], cbs[3];
#pragma unroll
    for (int i = 0; i < 2; i++) {
        const int c = t + i * 256;
        car[i] = c >> 2;
        cas[i] = (((c & 3) ^ ((car[i] >> 1) & 3)) * 8);
    }
#pragma unroll
    for (int i = 0; i < 3; i++) {
        const int c = t + i * 256;
        cbr[i] = c >> 2;
        cbs[i] = (((c & 3) ^ ((cbr[i] >> 1) & 3)) * 8);
    }

    f32x4 acc[4][6] = {};

#define STG_QKV(k0_, buf)                                                              \
    {                                                                                  \
        _Float16* ab = &As[(buf)][0][0];                                               \
        _Float16* bb = &Bs[(buf)][0][0];                                               \
        _Pragma("unroll") for (int i = 0; i < 2; i++)                                  \
            glds16(A + (size_t)(bm + car[i]) * K + (k0_) + cas[i], ab + (t + i * 256) * 8); \
        _Pragma("unroll") for (int i = 0; i < 3; i++)                                  \
            glds16(B + (size_t)(bn + cbr[i]) * K + (k0_) + cbs[i], bb + (t + i * 256) * 8); \
    }

    STG_QKV(0, 0)

    int cur = 0;
    for (int k0 = 0; k0 < K; k0 += 32) {
        __syncthreads();
        if (k0 + 32 < K) STG_QKV(k0 + 32, cur ^ 1)
        h8 af[4], bf[6];
#pragma unroll
        for (int m = 0; m < 4; m++) {
            const int row = wm * 64 + m * 16 + l15;
            af[m] = ld8h(&As[cur][row][(l4 ^ ((row >> 1) & 3)) * 8]);
        }
#pragma unroll
        for (int n = 0; n < 6; n++) {
            const int row = wn * 96 + n * 16 + l15;
            bf[n] = ld8h(&Bs[cur][row][(l4 ^ ((row >> 1) & 3)) * 8]);
        }
#pragma unroll
        for (int m = 0; m < 4; m++)
#pragma unroll
            for (int n = 0; n < 6; n++)
                acc[m][n] = __builtin_amdgcn_mfma_f32_16x16x32_f16(af[m], bf[n], acc[m][n], 0, 0, 0);
        cur ^= 1;
    }
#undef STG_QKV

    // epilogue: rope + split
    const int opcol0 = bn + wn * 96;
    const int which = opcol0 / 3072;          // 0=q 1=k 2=v (wave-uniform)
    const int h = (opcol0 % 3072) / 96;

    if (which == 2) {
#pragma unroll
        for (int m = 0; m < 4; m++)
#pragma unroll
            for (int r = 0; r < 4; r++) {
                const int l = bm + wm * 64 + m * 16 + l4 * 4 + r;
#pragma unroll
                for (int n = 0; n < 6; n++)
                    Vh[((size_t)h * 2048 + l) * 96 + n * 16 + l15] = (_Float16)acc[m][n][r];
            }
    } else {
        _Float16* dst = (which == 0) ? Qh : Kh;
        const float qs = (which == 0) ? attn_scale : 1.0f;
#pragma unroll
        for (int m = 0; m < 4; m++)
#pragma unroll
            for (int r = 0; r < 4; r++) {
                const int l = bm + wm * 64 + m * 16 + l4 * 4 + r;
                const float* csl = cs + l * 48;
                const float* snl = sn + l * 48;
                const size_t rowb = ((size_t)h * 2048 + l) * 96;
#pragma unroll
                for (int n = 0; n < 3; n++) {
                    const int j = n * 16 + l15;
                    const float c = csl[j], s = snl[j];
                    const float lo = acc[m][n][r], hi = acc[m][n + 3][r];
                    dst[rowb + j] = (_Float16)((lo * c - hi * s) * qs);
                    dst[rowb + j + 48] = (_Float16)((hi * c + lo * s) * qs);
                }
            }
    }
}

// ---------------------------------------------------------------------------
// C = A @ B^T fp16 MFMA (projection). 128x128, BK=32, dbuf, 0-conflict swizzle.
// ---------------------------------------------------------------------------
template <typename OT>
__global__ __launch_bounds__(256, 3) void gemm_t(
    const _Float16* __restrict__ A, const _Float16* __restrict__ B,
    OT* __restrict__ C, int M, int N, int K) {
    __shared__ _Float16 As[2][128][32], Bs[2][128][32];
    const int t = threadIdx.x;
    const int lane = t & 63, w = t >> 6;
    const int bm = blockIdx.y * 128, bn = blockIdx.x * 128;
    const int wy = w >> 1, wx = w & 1;
    const int l15 = lane & 15, l4 = lane >> 4;

    const int c0 = (w * 2 + 0) * 64 + lane;
    const int c1 = (w * 2 + 1) * 64 + lane;
    const int r0s = c0 >> 2, s0 = (((c0 & 3) ^ ((r0s >> 1) & 3)) * 8);
    const int r1s = c1 >> 2, s1 = (((c1 & 3) ^ ((r1s >> 1) & 3)) * 8);

    f32x4 acc[4][4] = {};

    glds16(A + (size_t)(bm + r0s) * K + s0, &As[0][0][0] + c0 * 8);
    glds16(A + (size_t)(bm + r1s) * K + s1, &As[0][0][0] + c1 * 8);
    glds16(B + (size_t)(bn + r0s) * K + s0, &Bs[0][0][0] + c0 * 8);
    glds16(B + (size_t)(bn + r1s) * K + s1, &Bs[0][0][0] + c1 * 8);

    int cry[4], crx[4];
#pragma unroll
    for (int m = 0; m < 4; m++) {
        const int rowA = wy * 64 + m * 16 + l15;
        cry[m] = ((l4 ^ ((rowA >> 1) & 3)) * 8);
        const int rowB = wx * 64 + m * 16 + l15;
        crx[m] = ((l4 ^ ((rowB >> 1) & 3)) * 8);
    }

    int cur = 0;
    for (int k0 = 0; k0 < K; k0 += 32) {
        __syncthreads();
        const int nk = k0 + 32;
        if (nk < K) {
            _Float16* an = &As[cur ^ 1][0][0];
            _Float16* bn_ = &Bs[cur ^ 1][0][0];
            glds16(A + (size_t)(bm + r0s) * K + nk + s0, an + c0 * 8);
            glds16(A + (size_t)(bm + r1s) * K + nk + s1, an + c1 * 8);
            glds16(B + (size_t)(bn + r0s) * K + nk + s0, bn_ + c0 * 8);
            glds16(B + (size_t)(bn + r1s) * K + nk + s1, bn_ + c1 * 8);
        }
        h8 af[4], bf[4];
#pragma unroll
        for (int m = 0; m < 4; m++) af[m] = ld8h(&As[cur][wy * 64 + m * 16 + l15][cry[m]]);
#pragma unroll
        for (int n = 0; n < 4; n++) bf[n] = ld8h(&Bs[cur][wx * 64 + n * 16 + l15][crx[n]]);
#pragma unroll
        for (int m = 0; m < 4; m++)
#pragma unroll
            for (int n = 0; n < 4; n++)
                acc[m][n] = __builtin_amdgcn_mfma_f32_16x16x32_f16(af[m], bf[n], acc[m][n], 0, 0, 0);
        cur ^= 1;
    }

#pragma unroll
    for (int m = 0; m < 4; m++)
#pragma unroll
        for (int n = 0; n < 4; n++)
#pragma unroll
            for (int r = 0; r < 4; r++)
                C[(size_t)(bm + wy * 64 + m * 16 + l4 * 4 + r) * N + bn + wx * 64 + n * 16 + l15] =
                    (OT)acc[m][n][r];
}

// ---------------------------------------------------------------------------
// V transpose: Vh [h][l][96] -> Vt[h][d][l] fp16.
// ---------------------------------------------------------------------------
__global__ __launch_bounds__(256) void vtrans(const _Float16* __restrict__ Vh,
                                              _Float16* __restrict__ Vt) {
    __shared__ _Float16 tile[64][105];
    const int h = blockIdx.y;
    const int l0 = blockIdx.x * 64;
    const int t = threadIdx.x;
#pragma unroll
    for (int i = 0; i < 3; i++) {
        const int v = t + i * 256;
        const int row = v / 12, seg = (v % 12) * 8;
        *(us8*)&tile[row][seg] =
            *(const us8*)(Vh + ((size_t)h * 2048 + l0 + row) * 96 + seg);
    }
    __syncthreads();
#pragma unroll
    for (int i = 0; i < 3; i++) {
        const int v = t + i * 256;
        const int d = v >> 3, lc = v & 7;
        h8 o;
#pragma unroll
        for (int j = 0; j < 8; j++) o[j] = tile[lc * 8 + j][d];
        *(h8*)(Vt + ((size_t)h * 96 + d) * 2048 + l0 + lc * 8) = o;
    }
}

// ---------------------------------------------------------------------------
// Flash attention, fp16 MFMA. Block = (256 q-rows, head) = 8 waves x 32 rows,
// 512 threads, grid 8x32 = 256 blocks (1/CU). Defer-max (T13) + deferred
// l-sum (per-lane partials, reduced once in the epilogue).
// ---------------------------------------------------------------------------
__global__ __launch_bounds__(512, 2) void attn_mfma(
    const _Float16* __restrict__ Qh, const _Float16* __restrict__ Kh,
    const _Float16* __restrict__ Vt, _Float16* __restrict__ Oh) {
    __shared__ _Float16 Ks[2][64][104];
    __shared__ _Float16 Vs[2][96][72];
    __shared__ _Float16 Ps[8][16][72];

    const int h = blockIdx.y;
    const int qt = 7 - (int)blockIdx.x;  // heavy blocks first
    const int q0 = qt * 256;
    const int t = threadIdx.x, lane = t & 63, w = t >> 6;
    const int l15 = lane & 15, l4 = lane >> 4;
    const int wq = q0 + w * 32;

    const _Float16* Kg = Kh + (size_t)h * 2048 * 96;
    const _Float16* Vg = Vt + (size_t)h * 96 * 2048;

    h8 qf[2][3];
#pragma unroll
    for (int g = 0; g < 2; g++) {
        const size_t qrow = ((size_t)h * 2048 + wq + g * 16 + l15) * 96;
#pragma unroll
        for (int kc = 0; kc < 3; kc++) qf[g][kc] = ld8h(Qh + qrow + kc * 32 + l4 * 8);
    }

    const int cA = t, rKA = cA / 12, sKA = (cA % 12) * 8;
    const int rVA = cA >> 3, sVA = (cA & 7) * 8;
    const int cB = 512 + t, rKB = cB / 12, sKB = (cB % 12) * 8;
    const int rVB = cB >> 3, sVB = (cB & 7) * 8;
    const bool two = (t < 256);

    us8 kregA, vregA, kregB, vregB;
    kregA = *(const us8*)(Kg + (size_t)rKA * 96 + sKA);
    vregA = *(const us8*)(Vg + (size_t)rVA * 2048 + sVA);
    if (two) {
        kregB = *(const us8*)(Kg + (size_t)rKB * 96 + sKB);
        vregB = *(const us8*)(Vg + (size_t)rVB * 2048 + sVB);
    }

    f32x4 o[2][6] = {};
    float m_i[2][4], l_i[2][4];
#pragma unroll
    for (int g = 0; g < 2; g++)
#pragma unroll
        for (int r = 0; r < 4; r++) { m_i[g][r] = -1e30f; l_i[g][r] = 0.f; }

    const int nkt = 4 * qt + 4;
    for (int kt = 0; kt < nkt; kt++) {
        const int kv0 = kt * 64;
        const int buf = kt & 1;
        *(us8*)&Ks[buf][rKA][sKA] = kregA;
        *(us8*)&Vs[buf][rVA][sVA] = vregA;
        if (two) {
            *(us8*)&Ks[buf][rKB][sKB] = kregB;
            *(us8*)&Vs[buf][rVB][sVB] = vregB;
        }
        __syncthreads();
        if (kt + 1 < nkt) {
            const int kv1 = kv0 + 64;
            kregA = *(const us8*)(Kg + (size_t)(kv1 + rKA) * 96 + sKA);
            vregA = *(const us8*)(Vg + (size_t)rVA * 2048 + kv1 + sVA);
            if (two) {
                kregB = *(const us8*)(Kg + (size_t)(kv1 + rKB) * 96 + sKB);
                vregB = *(const us8*)(Vg + (size_t)rVB * 2048 + kv1 + sVB);
            }
        }

        if (kv0 <= wq + 31) {
            f32x4 s[2][4] = {};
#pragma unroll
            for (int f = 0; f < 4; f++)
#pragma unroll
                for (int kc = 0; kc < 3; kc++) {
                    h8 kf = ld8h(&Ks[buf][f * 16 + l15][kc * 32 + l4 * 8]);
#pragma unroll
                    for (int g = 0; g < 2; g++)
                        s[g][f] = __builtin_amdgcn_mfma_f32_16x16x32_f16(qf[g][kc], kf, s[g][f], 0, 0, 0);
                }

            if (kv0 + 63 > wq) {
#pragma unroll
                for (int g = 0; g < 2; g++)
#pragma unroll
                    for (int f = 0; f < 4; f++)
#pragma unroll
                        for (int r = 0; r < 4; r++)
                            if (kv0 + f * 16 + l15 > wq + g * 16 + l4 * 4 + r) s[g][f][r] = -1e30f;
            }

            float mx[2][4];
#pragma unroll
            for (int g = 0; g < 2; g++)
#pragma unroll
                for (int r = 0; r < 4; r++) {
                    float m0 = fmaxf(fmaxf(s[g][0][r], s[g][1][r]), fmaxf(s[g][2][r], s[g][3][r]));
#pragma unroll
                    for (int msk = 1; msk < 16; msk <<= 1) m0 = fmaxf(m0, __shfl_xor(m0, msk, 64));
                    mx[g][r] = m0;
                }

            bool need = false;
#pragma unroll
            for (int g = 0; g < 2; g++)
#pragma unroll
                for (int r = 0; r < 4; r++) need = need || (mx[g][r] > m_i[g][r] + 8.0f);
            if (__any(need)) {
#pragma unroll
                for (int g = 0; g < 2; g++)
#pragma unroll
                    for (int r = 0; r < 4; r++) {
                        const float mnew = fmaxf(m_i[g][r], mx[g][r]);
                        const float sc = __expf(m_i[g][r] - mnew);
                        m_i[g][r] = mnew;
                        l_i[g][r] *= sc;
#pragma unroll
                        for (int f2 = 0; f2 < 6; f2++) o[g][f2][r] *= sc;
                    }
            }

#pragma unroll
            for (int g = 0; g < 2; g++) {
#pragma unroll
                for (int f = 0; f < 4; f++)
#pragma unroll
                    for (int r = 0; r < 4; r++) {
                        const float p = __expf(s[g][f][r] - m_i[g][r]);
                        Ps[w][l4 * 4 + r][f * 16 + l15] = (_Float16)p;
                        l_i[g][r] += p;   // per-lane partial; reduced in epilogue
                    }
#pragma unroll
                for (int kc2 = 0; kc2 < 2; kc2++) {
                    h8 pa = ld8h(&Ps[w][l15][kc2 * 32 + l4 * 8]);
#pragma unroll
                    for (int f2 = 0; f2 < 6; f2++) {
                        h8 vb = ld8h(&Vs[buf][f2 * 16 + l15][kc2 * 32 + l4 * 8]);
                        o[g][f2] = __builtin_amdgcn_mfma_f32_16x16x32_f16(pa, vb, o[g][f2], 0, 0, 0);
                    }
                }
            }
        }
    }

#pragma unroll
    for (int g = 0; g < 2; g++)
#pragma unroll
        for (int r = 0; r < 4; r++) {
            float ss = l_i[g][r];
#pragma unroll
            for (int msk = 1; msk < 16; msk <<= 1) ss += __shfl_xor(ss, msk, 64);
            const float inv = 1.0f / ss;
            const size_t row = (size_t)(wq + g * 16 + l4 * 4 + r) * 3072 + h * 96;
#pragma unroll
            for (int f2 = 0; f2 < 6; f2++)
                Oh[row + f2 * 16 + l15] = (_Float16)(o[g][f2][r] * inv);
        }
}

// ---------------------------------------------------------------------------
extern "C" void kernel_launch(void* const* d_in, const int* in_sizes, int n_in,
                              void* d_out, int out_size, void* d_ws, size_t ws_size,
                              hipStream_t stream) {
    const float* x = (const float*)d_in[0];
    const float* w_qkv = (const float*)d_in[1];
    const float* w_o = (const float*)d_in[2];
    const float* sf = (const float*)d_in[3];
    float* out = (float*)d_out;
    char* ws = (char*)d_ws;

    _Float16* wqkvh = (_Float16*)(ws);             // [0, 56.6MB)
    _Float16* Qh = (_Float16*)(ws + 56623104);
    _Float16* Kh = (_Float16*)(ws + 69206016);
    _Float16* Vh = (_Float16*)(ws + 81788928);
    _Float16* Vth = (_Float16*)(ws + 94371840);
    _Float16* Oh = (_Float16*)(ws + 106954752);
    _Float16* xh = (_Float16*)(ws + 132120576);
    _Float16* woh = (_Float16*)(ws + 144703488);
    float* cs = (float*)(ws + 163577856);
    float* sn = (float*)(ws + 163971072);

    const float rope_scale = (float)sqrt(1.0 + log(131072.0 / 4096.0) / log(4096.0));
    const float attn_scale = (float)(1.0 / sqrt(96.0));

    convert_half<<<3072, 256, 0, stream>>>(x, xh, 786432);
    convert_half<<<13824, 256, 0, stream>>>(w_qkv, wqkvh, 3538944);
    rope_table<<<384, 256, 0, stream>>>(sf, cs, sn, rope_scale);
    gemm_qkv<<<dim3(48, 16), 256, 0, stream>>>(xh, wqkvh, cs, sn, Qh, Kh, Vh, attn_scale);
    vtrans<<<dim3(32, 32), 256, 0, stream>>>(Vh, Vth);
    convert_half<<<4608, 256, 0, stream>>>(w_o, woh, 1179648);
    attn_mfma<<<dim3(8, 32), 512, 0, stream>>>(Qh, Kh, Vth, Oh);
    gemm_t<float><<<dim3(24, 16), 256, 0, stream>>>(Oh, woh, out, 2048, 3072, 3072);
}

// Round 12
// 317.608 us; speedup vs baseline: 1.7610x; 1.0739x over previous
//
#include <hip/hip_runtime.h>
#include <math.h>

typedef __attribute__((ext_vector_type(4))) float f32x4;
typedef __attribute__((ext_vector_type(4))) float f4;
typedef __attribute__((ext_vector_type(8))) _Float16 h8;
typedef __attribute__((ext_vector_type(8))) unsigned short us8;

static __device__ __forceinline__ h8 ld8h(const _Float16* p) {
    return __builtin_bit_cast(h8, *(const us8*)p);
}
static __device__ __forceinline__ void glds16(const void* g, void* l) {
    __builtin_amdgcn_global_load_lds((const __attribute__((address_space(1))) unsigned int*)g,
                                     (__attribute__((address_space(3))) unsigned int*)l, 16, 0, 0);
}

// ---------------------------------------------------------------------------
// fp32 -> fp16, 8 elements/thread
// ---------------------------------------------------------------------------
__global__ void convert_half(const float* __restrict__ in, _Float16* __restrict__ out, int n8) {
    int i = blockIdx.x * blockDim.x + threadIdx.x;
    if (i >= n8) return;
    f4 v0 = *(const f4*)(in + (size_t)i * 8);
    f4 v1 = *(const f4*)(in + (size_t)i * 8 + 4);
    h8 o;
#pragma unroll
    for (int j = 0; j < 4; j++) {
        o[j] = (_Float16)v0[j];
        o[j + 4] = (_Float16)v1[j];
    }
    *(h8*)(out + (size_t)i * 8) = o;
}

// ---------------------------------------------------------------------------
// SuRoPE cos/sin table: cs/sn[l][j] = cos/sin(l*inv_freq(j)) * rope_scale
// ---------------------------------------------------------------------------
__global__ void rope_table(const float* __restrict__ sf, float* __restrict__ cs,
                           float* __restrict__ sn, float rope_scale) {
    int i = blockIdx.x * blockDim.x + threadIdx.x;  // 2048*48
    const int j = i % 48, l = i / 48;
    const float e = (float)(2 * j) / 96.0f;
    const float inv = 1.0f / (sf[j] * powf(10000.0f, e));
    const float ang = (float)l * inv;
    cs[i] = cosf(ang) * rope_scale;
    sn[i] = sinf(ang) * rope_scale;
}

// ---------------------------------------------------------------------------
// QKV GEMM with fused SuRoPE + head-split epilogue. BM=128, BN=192,
// grid 48x16 = 768 blocks = exactly 3/CU. (MfmaUtil 37% = m97 ceiling.)
// ---------------------------------------------------------------------------
__global__ __launch_bounds__(256, 3) void gemm_qkv(
    const _Float16* __restrict__ A, const _Float16* __restrict__ B,
    const float* __restrict__ cs, const float* __restrict__ sn,
    _Float16* __restrict__ Qh, _Float16* __restrict__ Kh, _Float16* __restrict__ Vh,
    float attn_scale) {
    const int K = 3072;
    __shared__ _Float16 As[2][128][32], Bs[2][192][32];
    const int t = threadIdx.x;
    const int lane = t & 63, w = t >> 6;
    const int bm = blockIdx.y * 128, bn = blockIdx.x * 192;
    const int wm = w >> 1, wn = w & 1;
    const int l15 = lane & 15, l4 = lane >> 4;

    int car[2], cas[2], cbr[3], cbs[3];
#pragma unroll
    for (int i = 0; i < 2; i++) {
        const int c = t + i * 256;
        car[i] = c >> 2;
        cas[i] = (((c & 3) ^ ((car[i] >> 1) & 3)) * 8);
    }
#pragma unroll
    for (int i = 0; i < 3; i++) {
        const int c = t + i * 256;
        cbr[i] = c >> 2;
        cbs[i] = (((c & 3) ^ ((cbr[i] >> 1) & 3)) * 8);
    }

    f32x4 acc[4][6] = {};

#define STG_QKV(k0_, buf)                                                              \
    {                                                                                  \
        _Float16* ab = &As[(buf)][0][0];                                               \
        _Float16* bb = &Bs[(buf)][0][0];                                               \
        _Pragma("unroll") for (int i = 0; i < 2; i++)                                  \
            glds16(A + (size_t)(bm + car[i]) * K + (k0_) + cas[i], ab + (t + i * 256) * 8); \
        _Pragma("unroll") for (int i = 0; i < 3; i++)                                  \
            glds16(B + (size_t)(bn + cbr[i]) * K + (k0_) + cbs[i], bb + (t + i * 256) * 8); \
    }

    STG_QKV(0, 0)

    int cur = 0;
    for (int k0 = 0; k0 < K; k0 += 32) {
        __syncthreads();
        if (k0 + 32 < K) STG_QKV(k0 + 32, cur ^ 1)
        h8 af[4], bf[6];
#pragma unroll
        for (int m = 0; m < 4; m++) {
            const int row = wm * 64 + m * 16 + l15;
            af[m] = ld8h(&As[cur][row][(l4 ^ ((row >> 1) & 3)) * 8]);
        }
#pragma unroll
        for (int n = 0; n < 6; n++) {
            const int row = wn * 96 + n * 16 + l15;
            bf[n] = ld8h(&Bs[cur][row][(l4 ^ ((row >> 1) & 3)) * 8]);
        }
#pragma unroll
        for (int m = 0; m < 4; m++)
#pragma unroll
            for (int n = 0; n < 6; n++)
                acc[m][n] = __builtin_amdgcn_mfma_f32_16x16x32_f16(af[m], bf[n], acc[m][n], 0, 0, 0);
        cur ^= 1;
    }
#undef STG_QKV

    const int opcol0 = bn + wn * 96;
    const int which = opcol0 / 3072;
    const int h = (opcol0 % 3072) / 96;

    if (which == 2) {
#pragma unroll
        for (int m = 0; m < 4; m++)
#pragma unroll
            for (int r = 0; r < 4; r++) {
                const int l = bm + wm * 64 + m * 16 + l4 * 4 + r;
#pragma unroll
                for (int n = 0; n < 6; n++)
                    Vh[((size_t)h * 2048 + l) * 96 + n * 16 + l15] = (_Float16)acc[m][n][r];
            }
    } else {
        _Float16* dst = (which == 0) ? Qh : Kh;
        const float qs = (which == 0) ? attn_scale : 1.0f;
#pragma unroll
        for (int m = 0; m < 4; m++)
#pragma unroll
            for (int r = 0; r < 4; r++) {
                const int l = bm + wm * 64 + m * 16 + l4 * 4 + r;
                const float* csl = cs + l * 48;
                const float* snl = sn + l * 48;
                const size_t rowb = ((size_t)h * 2048 + l) * 96;
#pragma unroll
                for (int n = 0; n < 3; n++) {
                    const int j = n * 16 + l15;
                    const float c = csl[j], s = snl[j];
                    const float lo = acc[m][n][r], hi = acc[m][n + 3][r];
                    dst[rowb + j] = (_Float16)((lo * c - hi * s) * qs);
                    dst[rowb + j + 48] = (_Float16)((hi * c + lo * s) * qs);
                }
            }
    }
}

// ---------------------------------------------------------------------------
// Projection GEMM: C = A @ B^T, BM=128, BN=96 -> grid 32x16 = 512 blocks =
// uniform 2/CU (was 384/768 slots = 75% packing). 4 waves 2x2, per-wave
// 64x48 (4x3 frags). Same 0-conflict swizzle.
// ---------------------------------------------------------------------------
__global__ __launch_bounds__(256, 3) void gemm_p(
    const _Float16* __restrict__ A, const _Float16* __restrict__ B,
    float* __restrict__ C, int M, int N, int K) {
    __shared__ _Float16 As[2][128][32], Bs[2][96][32];
    const int t = threadIdx.x;
    const int lane = t & 63, w = t >> 6;
    const int bm = blockIdx.y * 128, bn = blockIdx.x * 96;
    const int wy = w >> 1, wx = w & 1;
    const int l15 = lane & 15, l4 = lane >> 4;

    // A: 512 chunks (2/thr). B: 384 chunks = all threads + waves 0-1 2nd pass.
    int car[2], cas[2];
#pragma unroll
    for (int i = 0; i < 2; i++) {
        const int c = t + i * 256;
        car[i] = c >> 2;
        cas[i] = (((c & 3) ^ ((car[i] >> 1) & 3)) * 8);
    }
    const int cb0 = t, rb0 = cb0 >> 2, sb0 = (((cb0 & 3) ^ ((rb0 >> 1) & 3)) * 8);
    const int cb1 = t + 256, rb1 = cb1 >> 2, sb1 = (((cb1 & 3) ^ ((rb1 >> 1) & 3)) * 8);
    const bool bex = (t < 128);

    f32x4 acc[4][3] = {};

#define STG_P(k0_, buf)                                                                \
    {                                                                                  \
        _Float16* ab = &As[(buf)][0][0];                                               \
        _Float16* bb = &Bs[(buf)][0][0];                                               \
        _Pragma("unroll") for (int i = 0; i < 2; i++)                                  \
            glds16(A + (size_t)(bm + car[i]) * K + (k0_) + cas[i], ab + (t + i * 256) * 8); \
        glds16(B + (size_t)(bn + rb0) * K + (k0_) + sb0, bb + cb0 * 8);                \
        if (bex) glds16(B + (size_t)(bn + rb1) * K + (k0_) + sb1, bb + cb1 * 8);       \
    }

    STG_P(0, 0)

    int cur = 0;
    for (int k0 = 0; k0 < K; k0 += 32) {
        __syncthreads();
        if (k0 + 32 < K) STG_P(k0 + 32, cur ^ 1)
        h8 af[4], bf[3];
#pragma unroll
        for (int m = 0; m < 4; m++) {
            const int row = wy * 64 + m * 16 + l15;
            af[m] = ld8h(&As[cur][row][(l4 ^ ((row >> 1) & 3)) * 8]);
        }
#pragma unroll
        for (int n = 0; n < 3; n++) {
            const int row = wx * 48 + n * 16 + l15;
            bf[n] = ld8h(&Bs[cur][row][(l4 ^ ((row >> 1) & 3)) * 8]);
        }
#pragma unroll
        for (int m = 0; m < 4; m++)
#pragma unroll
            for (int n = 0; n < 3; n++)
                acc[m][n] = __builtin_amdgcn_mfma_f32_16x16x32_f16(af[m], bf[n], acc[m][n], 0, 0, 0);
        cur ^= 1;
    }
#undef STG_P

#pragma unroll
    for (int m = 0; m < 4; m++)
#pragma unroll
        for (int n = 0; n < 3; n++)
#pragma unroll
            for (int r = 0; r < 4; r++)
                C[(size_t)(bm + wy * 64 + m * 16 + l4 * 4 + r) * N + bn + wx * 48 + n * 16 + l15] =
                    acc[m][n][r];
}

// ---------------------------------------------------------------------------
// V transpose: Vh [h][l][96] -> Vt[h][d][l] fp16.
// ---------------------------------------------------------------------------
__global__ __launch_bounds__(256) void vtrans(const _Float16* __restrict__ Vh,
                                              _Float16* __restrict__ Vt) {
    __shared__ _Float16 tile[64][105];
    const int h = blockIdx.y;
    const int l0 = blockIdx.x * 64;
    const int t = threadIdx.x;
#pragma unroll
    for (int i = 0; i < 3; i++) {
        const int v = t + i * 256;
        const int row = v / 12, seg = (v % 12) * 8;
        *(us8*)&tile[row][seg] =
            *(const us8*)(Vh + ((size_t)h * 2048 + l0 + row) * 96 + seg);
    }
    __syncthreads();
#pragma unroll
    for (int i = 0; i < 3; i++) {
        const int v = t + i * 256;
        const int d = v >> 3, lc = v & 7;
        h8 o;
#pragma unroll
        for (int j = 0; j < 8; j++) o[j] = tile[lc * 8 + j][d];
        *(h8*)(Vt + ((size_t)h * 96 + d) * 2048 + l0 + lc * 8) = o;
    }
}

// ---------------------------------------------------------------------------
// Flash attention, fp16 MFMA, DIAGONAL-PAIRED for uniform load:
// block (bx, h) processes q-tile (15-bx) then q-tile (bx), QBLK=128 each
// (8 waves x 16 rows). Total work = 17 KV-tiles for EVERY block; grid
// 8x32 = 256 blocks = 1/CU, zero tail. Defer-max (T13) + deferred l-sum.
// ---------------------------------------------------------------------------
__global__ __launch_bounds__(512, 2) void attn_mfma(
    const _Float16* __restrict__ Qh, const _Float16* __restrict__ Kh,
    const _Float16* __restrict__ Vt, _Float16* __restrict__ Oh) {
    __shared__ _Float16 Ks[2][64][104];
    __shared__ _Float16 Vs[2][96][72];
    __shared__ _Float16 Ps[8][16][72];

    const int h = blockIdx.y;
    const int t = threadIdx.x, lane = t & 63, w = t >> 6;
    const int l15 = lane & 15, l4 = lane >> 4;

    const _Float16* Kg = Kh + (size_t)h * 2048 * 96;
    const _Float16* Vg = Vt + (size_t)h * 96 * 2048;

    // staging geometry: K tile 64x96 = 768 chunks, V tile 96x64 = 768 chunks;
    // chunk cA = t (all 8 waves), chunk cB = 512+t (waves 0-3).
    const int cA = t, rKA = cA / 12, sKA = (cA % 12) * 8;
    const int rVA = cA >> 3, sVA = (cA & 7) * 8;
    const int cB = 512 + t, rKB = cB / 12, sKB = (cB % 12) * 8;
    const int rVB = cB >> 3, sVB = (cB & 7) * 8;
    const bool two = (t < 256);

    for (int ph = 0; ph < 2; ph++) {
        const int qt = ph ? (int)blockIdx.x : 15 - (int)blockIdx.x;
        const int q0 = qt * 128;
        const int wq = q0 + w * 16;

        h8 qf[3];
        const size_t qrow = ((size_t)h * 2048 + wq + l15) * 96;
#pragma unroll
        for (int kc = 0; kc < 3; kc++) qf[kc] = ld8h(Qh + qrow + kc * 32 + l4 * 8);

        us8 kregA, vregA, kregB, vregB;
        kregA = *(const us8*)(Kg + (size_t)rKA * 96 + sKA);
        vregA = *(const us8*)(Vg + (size_t)rVA * 2048 + sVA);
        if (two) {
            kregB = *(const us8*)(Kg + (size_t)rKB * 96 + sKB);
            vregB = *(const us8*)(Vg + (size_t)rVB * 2048 + sVB);
        }

        f32x4 o[6] = {};
        float m_i[4] = {-1e30f, -1e30f, -1e30f, -1e30f};
        float l_i[4] = {0.f, 0.f, 0.f, 0.f};

        const int nkt = 2 * qt + 2;
        for (int kt = 0; kt < nkt; kt++) {
            const int kv0 = kt * 64;
            const int buf = kt & 1;
            *(us8*)&Ks[buf][rKA][sKA] = kregA;
            *(us8*)&Vs[buf][rVA][sVA] = vregA;
            if (two) {
                *(us8*)&Ks[buf][rKB][sKB] = kregB;
                *(us8*)&Vs[buf][rVB][sVB] = vregB;
            }
            __syncthreads();
            if (kt + 1 < nkt) {  // prefetch next tile into regs (T14)
                const int kv1 = kv0 + 64;
                kregA = *(const us8*)(Kg + (size_t)(kv1 + rKA) * 96 + sKA);
                vregA = *(const us8*)(Vg + (size_t)rVA * 2048 + kv1 + sVA);
                if (two) {
                    kregB = *(const us8*)(Kg + (size_t)(kv1 + rKB) * 96 + sKB);
                    vregB = *(const us8*)(Vg + (size_t)rVB * 2048 + kv1 + sVB);
                }
            }

            if (kv0 <= wq + 15) {  // tile visible to this wave
                f32x4 s[4] = {};
#pragma unroll
                for (int f = 0; f < 4; f++)
#pragma unroll
                    for (int kc = 0; kc < 3; kc++) {
                        h8 kf = ld8h(&Ks[buf][f * 16 + l15][kc * 32 + l4 * 8]);
                        s[f] = __builtin_amdgcn_mfma_f32_16x16x32_f16(qf[kc], kf, s[f], 0, 0, 0);
                    }

                if (kv0 + 63 > wq) {  // diagonal-crossing: causal mask
#pragma unroll
                    for (int f = 0; f < 4; f++)
#pragma unroll
                        for (int r = 0; r < 4; r++)
                            if (kv0 + f * 16 + l15 > wq + l4 * 4 + r) s[f][r] = -1e30f;
                }

                float mx[4];
#pragma unroll
                for (int r = 0; r < 4; r++) {
                    float m0 = fmaxf(fmaxf(s[0][r], s[1][r]), fmaxf(s[2][r], s[3][r]));
#pragma unroll
                    for (int msk = 1; msk < 16; msk <<= 1) m0 = fmaxf(m0, __shfl_xor(m0, msk, 64));
                    mx[r] = m0;
                }

                bool need = false;
#pragma unroll
                for (int r = 0; r < 4; r++) need = need || (mx[r] > m_i[r] + 8.0f);
                if (__any(need)) {
#pragma unroll
                    for (int r = 0; r < 4; r++) {
                        const float mnew = fmaxf(m_i[r], mx[r]);
                        const float sc = __expf(m_i[r] - mnew);
                        m_i[r] = mnew;
                        l_i[r] *= sc;
#pragma unroll
                        for (int f2 = 0; f2 < 6; f2++) o[f2][r] *= sc;
                    }
                }

#pragma unroll
                for (int f = 0; f < 4; f++)
#pragma unroll
                    for (int r = 0; r < 4; r++) {
                        const float p = __expf(s[f][r] - m_i[r]);
                        Ps[w][l4 * 4 + r][f * 16 + l15] = (_Float16)p;
                        l_i[r] += p;  // per-lane partial; reduced in epilogue
                    }
#pragma unroll
                for (int kc2 = 0; kc2 < 2; kc2++) {
                    h8 pa = ld8h(&Ps[w][l15][kc2 * 32 + l4 * 8]);
#pragma unroll
                    for (int f2 = 0; f2 < 6; f2++) {
                        h8 vb = ld8h(&Vs[buf][f2 * 16 + l15][kc2 * 32 + l4 * 8]);
                        o[f2] = __builtin_amdgcn_mfma_f32_16x16x32_f16(pa, vb, o[f2], 0, 0, 0);
                    }
                }
            }
        }

        __syncthreads();  // all waves done with LDS before next phase restages

#pragma unroll
        for (int r = 0; r < 4; r++) {
            float ss = l_i[r];
#pragma unroll
            for (int msk = 1; msk < 16; msk <<= 1) ss += __shfl_xor(ss, msk, 64);
            const float inv = 1.0f / ss;
            const size_t row = (size_t)(wq + l4 * 4 + r) * 3072 + h * 96;
#pragma unroll
            for (int f2 = 0; f2 < 6; f2++)
                Oh[row + f2 * 16 + l15] = (_Float16)(o[f2][r] * inv);
        }
    }
}

// ---------------------------------------------------------------------------
extern "C" void kernel_launch(void* const* d_in, const int* in_sizes, int n_in,
                              void* d_out, int out_size, void* d_ws, size_t ws_size,
                              hipStream_t stream) {
    const float* x = (const float*)d_in[0];
    const float* w_qkv = (const float*)d_in[1];
    const float* w_o = (const float*)d_in[2];
    const float* sf = (const float*)d_in[3];
    float* out = (float*)d_out;
    char* ws = (char*)d_ws;

    _Float16* wqkvh = (_Float16*)(ws);             // [0, 56.6MB)
    _Float16* Qh = (_Float16*)(ws + 56623104);
    _Float16* Kh = (_Float16*)(ws + 69206016);
    _Float16* Vh = (_Float16*)(ws + 81788928);
    _Float16* Vth = (_Float16*)(ws + 94371840);
    _Float16* Oh = (_Float16*)(ws + 106954752);
    _Float16* xh = (_Float16*)(ws + 132120576);
    _Float16* woh = (_Float16*)(ws + 144703488);
    float* cs = (float*)(ws + 163577856);
    float* sn = (float*)(ws + 163971072);

    const float rope_scale = (float)sqrt(1.0 + log(131072.0 / 4096.0) / log(4096.0));
    const float attn_scale = (float)(1.0 / sqrt(96.0));

    convert_half<<<3072, 256, 0, stream>>>(x, xh, 786432);
    convert_half<<<13824, 256, 0, stream>>>(w_qkv, wqkvh, 3538944);
    rope_table<<<384, 256, 0, stream>>>(sf, cs, sn, rope_scale);
    gemm_qkv<<<dim3(48, 16), 256, 0, stream>>>(xh, wqkvh, cs, sn, Qh, Kh, Vh, attn_scale);
    vtrans<<<dim3(32, 32), 256, 0, stream>>>(Vh, Vth);
    convert_half<<<4608, 256, 0, stream>>>(w_o, woh, 1179648);
    attn_mfma<<<dim3(8, 32), 512, 0, stream>>>(Qh, Kh, Vth, Oh);
    gemm_p<<<dim3(32, 16), 256, 0, stream>>>(Oh, woh, out, 2048, 3072, 3072);
}